// Round 1
// baseline (8165.060 us; speedup 1.0000x reference)
//
#include <hip/hip_runtime.h>
#include <stdint.h>

typedef unsigned short u16;
typedef __attribute__((ext_vector_type(8))) short bf16x8;   // 8 bf16 in 4 VGPRs
typedef __attribute__((ext_vector_type(4))) short s16x4;
typedef __attribute__((ext_vector_type(4))) float f32x4;

static constexpr int BATCH = 64;
static constexpr int SEQ   = 512;
static constexpr int HID   = 1024;           // == IN_F == OUT_F
static constexpr int M_ALL = BATCH * SEQ;    // 32768

__device__ __forceinline__ u16 f2bf(float f) {
  union { float f; uint32_t u; } v; v.f = f;
  uint32_t r = (v.u + 0x7fffu + ((v.u >> 16) & 1u)) >> 16;  // RNE
  return (u16)r;
}
__device__ __forceinline__ float bf2f(u16 u) {
  union { float f; uint32_t u; } v; v.u = ((uint32_t)u) << 16;
  return v.f;
}

__device__ __forceinline__ void gload_lds16(const void* g, void* l) {
  __builtin_amdgcn_global_load_lds(
      (const __attribute__((address_space(1))) void*)g,
      (__attribute__((address_space(3))) void*)l, 16, 0, 0);
}

// ---------------------------------------------------------------- converts
__global__ __launch_bounds__(256) void k_convert_weights(
    const float* __restrict__ Wih, const float* __restrict__ Who,
    u16* __restrict__ Wx, u16* __restrict__ Wh, u16* __restrict__ Whob) {
  int idx = blockIdx.x * 256 + threadIdx.x;     // float4 index, 3*262144 total
  int mat = idx >> 18;
  int e   = (idx & 262143) << 2;                // element index within matrix
  int row = e >> 10, col = e & 1023;
  const float* src;
  u16* dst;
  if (mat == 0)      { src = Wih + row * 2048 + col;        dst = Wx   + e; }
  else if (mat == 1) { src = Wih + row * 2048 + 1024 + col; dst = Wh   + e; }
  else               { src = Who + e;                       dst = Whob + e; }
  f32x4 v = *(const f32x4*)src;
  s16x4 o;
  o[0] = (short)f2bf(v[0]); o[1] = (short)f2bf(v[1]);
  o[2] = (short)f2bf(v[2]); o[3] = (short)f2bf(v[3]);
  *(s16x4*)dst = o;
}

__global__ __launch_bounds__(256) void k_convert_x(const float* __restrict__ x,
                                                   u16* __restrict__ xb) {
  const int n4 = M_ALL * HID / 4;  // 8388608
  for (int i = blockIdx.x * 256 + threadIdx.x; i < n4; i += gridDim.x * 256) {
    f32x4 v = *(const f32x4*)(x + (size_t)i * 4);
    s16x4 o;
    o[0] = (short)f2bf(v[0]); o[1] = (short)f2bf(v[1]);
    o[2] = (short)f2bf(v[2]); o[3] = (short)f2bf(v[3]);
    *(s16x4*)(xb + (size_t)i * 4) = o;
  }
}

__global__ __launch_bounds__(256) void k_init(const float* __restrict__ h0,
                                              u16* __restrict__ hbuf,
                                              uint32_t* __restrict__ flags) {
  int i = blockIdx.x * 256 + threadIdx.x;       // 65536 = 64 x 1024
  hbuf[i] = f2bf(h0[i]);                        // h_buf[0][b][k] flat == h0 layout
  if (blockIdx.x == 0 && threadIdx.x < 4) flags[threadIdx.x * 32] = 0;
}

// ---------------------------------------------------------------- big GEMMs
// MODE 0: XP[m=s*64+b][n] (bf16) = x[b][s][:] @ Wx^T + b_ih   (A rows permuted)
// MODE 1: out[b][s][n] (f32)     = Hall[m][:]  @ Who^T + b_ho (C rows permuted)
template <int MODE>
__global__ __launch_bounds__(256) void k_gemm(const u16* __restrict__ A,
                                              const u16* __restrict__ Bw,
                                              const float* __restrict__ bias,
                                              u16* __restrict__ obf,
                                              float* __restrict__ of32) {
  __shared__ alignas(16) u16 As[128 * 32];
  __shared__ alignas(16) u16 Bs[128 * 32];
  const int tid = threadIdx.x;
  const int lane = tid & 63, wave = tid >> 6;
  const int bm = blockIdx.x >> 3, bn = blockIdx.x & 7;
  const int m0 = bm * 128, n0 = bn * 128;

  const int lr0 = wave * 16 + (lane >> 2);        // staging row, pass 0
  const int lr1 = (4 + wave) * 16 + (lane >> 2);  // staging row, pass 1
  const int koff = (lane & 3) * 8;                // ushort offset in row (16B)

  const int r0 = m0 + lr0, r1 = m0 + lr1;
  const u16* ag0; const u16* ag1;
  if (MODE == 0) {
    ag0 = A + (size_t)(((r0 & 63) * 512 + (r0 >> 6))) * 1024 + koff;
    ag1 = A + (size_t)(((r1 & 63) * 512 + (r1 >> 6))) * 1024 + koff;
  } else {
    ag0 = A + (size_t)r0 * 1024 + koff;
    ag1 = A + (size_t)r1 * 1024 + koff;
  }
  const u16* bg0 = Bw + (size_t)(n0 + lr0) * 1024 + koff;
  const u16* bg1 = Bw + (size_t)(n0 + lr1) * 1024 + koff;
  u16* al0 = As + lr0 * 32 + koff;   // byte addr == wave*1024 + lane*16 (linear)
  u16* al1 = As + lr1 * 32 + koff;
  u16* bl0 = Bs + lr0 * 32 + koff;
  u16* bl1 = Bs + lr1 * 32 + koff;

  const int wr = (wave >> 1) * 64, wc = (wave & 1) * 64;
  f32x4 zero = {0.f, 0.f, 0.f, 0.f};
  f32x4 acc[4][4];
#pragma unroll
  for (int i = 0; i < 4; i++)
#pragma unroll
    for (int j = 0; j < 4; j++) acc[i][j] = zero;

  for (int k0 = 0; k0 < 1024; k0 += 32) {
    __syncthreads();                       // previous tile's ds_reads done
    gload_lds16(ag0 + k0, al0);
    gload_lds16(ag1 + k0, al1);
    gload_lds16(bg0 + k0, bl0);
    gload_lds16(bg1 + k0, bl1);
    __syncthreads();                       // vmcnt drained -> LDS tile ready

    bf16x8 af[4], bfr[4];
#pragma unroll
    for (int i = 0; i < 4; i++) {
      af[i]  = *(const bf16x8*)(As + (wr + i * 16 + (lane & 15)) * 32 + (lane >> 4) * 8);
      bfr[i] = *(const bf16x8*)(Bs + (wc + i * 16 + (lane & 15)) * 32 + (lane >> 4) * 8);
    }
#pragma unroll
    for (int i = 0; i < 4; i++)
#pragma unroll
      for (int j = 0; j < 4; j++)
        acc[i][j] = __builtin_amdgcn_mfma_f32_16x16x32_bf16(af[i], bfr[j], acc[i][j], 0, 0, 0);
  }

#pragma unroll
  for (int i = 0; i < 4; i++) {
    const int grow_b = m0 + wr + i * 16 + (lane >> 4) * 4;
#pragma unroll
    for (int j = 0; j < 4; j++) {
      const int gcol = n0 + wc + j * 16 + (lane & 15);
      const float bv = bias[gcol];
#pragma unroll
      for (int r = 0; r < 4; r++) {
        const int grow = grow_b + r;
        const float v = acc[i][j][r] + bv;
        if (MODE == 0) {
          obf[(size_t)grow * 1024 + gcol] = f2bf(v);
        } else {
          of32[(size_t)((grow & 63) * 512 + (grow >> 6)) * 1024 + gcol] = v;
        }
      }
    }
  }
}

// ---------------------------------------------------------------- recurrence
// 256 WGs x 64 threads. group g = wg&3 owns batches [16g,16g+16); WG owns
// HID cols [n0, n0+16). W_h slice LDS-resident. Per step: MFMA 16x16x(32*32),
// tanh, store h (bf16 dbuf) + Hall, group barrier via agent-scope atomics.
__global__ __launch_bounds__(64) void k_rnn(const u16* __restrict__ Wh,
                                            const u16* __restrict__ XP,
                                            u16* __restrict__ hbuf,
                                            u16* __restrict__ Hall,
                                            uint32_t* __restrict__ flags) {
  __shared__ alignas(16) u16 WhL[16][1032];     // +8 u16 pad: 2-way-free banks
  const int lane = threadIdx.x;
  const int wg = blockIdx.x;
  const int g = wg & 3;
  const int n0 = (wg >> 2) * 16;

  // one-time: W_h rows n0..n0+15 -> LDS (32 KB)
  for (int row = 0; row < 16; row++) {
    const u16* src = Wh + (size_t)(n0 + row) * 1024;
#pragma unroll
    for (int c = 0; c < 2; c++) {
      int e = (lane + c * 64) * 8;
      *(bf16x8*)&WhL[row][e] = *(const bf16x8*)(src + e);
    }
  }
  __syncthreads();

  const int arow = lane & 15;          // A row (batch within group)
  const int koff8 = (lane >> 4) * 8;   // A/B k offset
  const int dcol = lane & 15;          // D col (HID col within slice)
  const int brow_b = (lane >> 4) * 4;  // D rows base
  uint32_t* flg = flags + g * 32;
  const int HB = 65536;                // u16 per h buffer (64x1024)
  f32x4 zero = {0.f, 0.f, 0.f, 0.f};

  for (int t = 0; t < SEQ; t++) {
    const u16* hsrc = hbuf + (t & 1) * HB + g * 16384 + arow * 1024 + koff8;
    f32x4 acc0 = zero, acc1 = zero;
#pragma unroll
    for (int kt = 0; kt < 32; kt += 2) {
      bf16x8 a0 = *(const bf16x8*)(hsrc + kt * 32);
      bf16x8 b0 = *(const bf16x8*)&WhL[dcol][kt * 32 + koff8];
      acc0 = __builtin_amdgcn_mfma_f32_16x16x32_bf16(a0, b0, acc0, 0, 0, 0);
      bf16x8 a1 = *(const bf16x8*)(hsrc + (kt + 1) * 32);
      bf16x8 b1 = *(const bf16x8*)&WhL[dcol][(kt + 1) * 32 + koff8];
      acc1 = __builtin_amdgcn_mfma_f32_16x16x32_bf16(a1, b1, acc1, 0, 0, 0);
    }

    u16* hdst = hbuf + ((t + 1) & 1) * HB + g * 16384;
#pragma unroll
    for (int r = 0; r < 4; r++) {
      const int brow = brow_b + r;
      const int b = g * 16 + brow;
      const float xpv = bf2f(XP[(size_t)(t * 64 + b) * 1024 + n0 + dcol]);
      const float hn = tanhf(acc0[r] + acc1[r] + xpv);
      const u16 hb = f2bf(hn);
      hdst[brow * 1024 + n0 + dcol] = hb;
      Hall[(size_t)(t * 64 + b) * 1024 + n0 + dcol] = hb;
    }

    // ---- group barrier (agent-scope; correct regardless of XCD placement)
    __threadfence();                               // release my stores
    if (lane == 0) {
      atomicAdd(flg, 1u);
      const uint32_t target = 64u * (t + 1);
      while (__hip_atomic_load(flg, __ATOMIC_RELAXED, __HIP_MEMORY_SCOPE_AGENT) < target)
        __builtin_amdgcn_s_sleep(2);
    }
    __syncthreads();
    __threadfence();                               // acquire: see fresh h
  }
}

// ---------------------------------------------------------------- launch
extern "C" void kernel_launch(void* const* d_in, const int* in_sizes, int n_in,
                              void* d_out, int out_size, void* d_ws, size_t ws_size,
                              hipStream_t stream) {
  const float* x   = (const float*)d_in[0];
  const float* h0  = (const float*)d_in[1];
  const float* Wih = (const float*)d_in[2];
  const float* bih = (const float*)d_in[3];
  const float* Who = (const float*)d_in[4];
  const float* bho = (const float*)d_in[5];
  float* out = (float*)d_out;

  char* ws = (char*)d_ws;
  size_t off = 0;
  auto alloc = [&](size_t bytes) {
    void* p = ws + off;
    off = (off + bytes + 255) & ~(size_t)255;
    return p;
  };
  uint32_t* flags = (uint32_t*)alloc(4096);
  u16* hbuf  = (u16*)alloc(2 * 65536 * sizeof(u16));            // 256 KB
  u16* Wx    = (u16*)alloc((size_t)1024 * 1024 * 2);
  u16* Wh    = (u16*)alloc((size_t)1024 * 1024 * 2);
  u16* Whob  = (u16*)alloc((size_t)1024 * 1024 * 2);
  u16* xb    = (u16*)alloc((size_t)M_ALL * 1024 * 2);           // 64 MB
  u16* XP    = (u16*)alloc((size_t)M_ALL * 1024 * 2);           // 64 MB
  u16* Hall  = (u16*)alloc((size_t)M_ALL * 1024 * 2);           // 64 MB

  k_convert_weights<<<3072, 256, 0, stream>>>(Wih, Who, Wx, Wh, Whob);
  k_convert_x<<<4096, 256, 0, stream>>>(x, xb);
  k_init<<<256, 256, 0, stream>>>(h0, hbuf, flags);
  k_gemm<0><<<2048, 256, 0, stream>>>(xb, Wx, bih, XP, nullptr);
  k_rnn<<<256, 64, 0, stream>>>(Wh, XP, hbuf, Hall, flags);
  k_gemm<1><<<2048, 256, 0, stream>>>(Hall, Whob, bho, nullptr, out);
}